// Round 9
// baseline (440.510 us; speedup 1.0000x reference)
//
#include <hip/hip_runtime.h>
#include <cstdint>

#define B_    64
#define NV_   6890
#define NF_   13776
#define NHD_  20000
#define NP_   24
#define NCH   216           // ceil(6890/32) k-chunks of 32
#define ITERS 108           // chunks per K-split (216/2)
#define BUF_HW 6144         // halfwords per B buffer (12 tiles * 64 lanes * 8) = 12 KB

// ---------------- workspace layout (bytes) ----------------
#define OFF_PPV   0u        // ppv [64][24] f32   6144   (zeroed by k_init)
#define OFF_RED   6144u     // red [64][6]  f32   1536   (zeroed by k_init)
#define OFF_VC    7680u     // Vc [216][12][64][8] bf16 = 2,654,208 B (fully rewritten)

typedef __attribute__((ext_vector_type(8))) __bf16 bf16x8;
typedef __attribute__((ext_vector_type(4))) float f32x4;

__device__ __forceinline__ unsigned short f2bf(float f) {
    unsigned u = __float_as_uint(f);
    u = (u + 0x7fffu + ((u >> 16) & 1u)) >> 16;   // RNE (no NaNs here)
    return (unsigned short)u;
}

// ---------------- K_init: zero ppv + red ----------------
__global__ __launch_bounds__(256) void k_init(float* __restrict__ z) {
    for (int i = threadIdx.x; i < 1920; i += 256) z[i] = 0.f;   // 1536 ppv + 384 red
}

// ---------------- K0v: pack V into MFMA-fragment order ----------------
// Vc[((c*12 + t)*64 + lane)*8 + j] = V_bf16[bd = t*16 + (lane&15)][k = c*32 + (lane>>4)*8 + j]
__global__ __launch_bounds__(256) void k0v_pack(const float* __restrict__ verts,
                                                unsigned short* __restrict__ Vc) {
    int idx = blockIdx.x * 256 + threadIdx.x;       // 216*12*512 = 1,327,104 total
    int j    = idx & 7;
    int lane = (idx >> 3) & 63;
    int ct   = idx >> 9;                            // c*12 + t
    int t    = ct % 12;
    int c    = ct / 12;
    int lm   = lane & 15;
    int kk   = (lane >> 4) * 8 + j;
    int bd   = t * 16 + lm;
    int d    = bd >> 6, b = bd & 63;
    int k    = c * 32 + kk;
    float v  = (k < NV_) ? verts[((size_t)b * NV_ + k) * 3 + d] : 0.f;
    Vc[idx] = f2bf(v);
}

// ---------------- K1: per-part volumes ----------------
__global__ __launch_bounds__(256) void k1_vol(const float* __restrict__ verts,
                                              const int* __restrict__ faces,
                                              const int* __restrict__ face_part,
                                              float* __restrict__ ppv) {
    __shared__ float bins[NP_];
    int b = blockIdx.y;
    int f = blockIdx.x * 256 + threadIdx.x;
    if (threadIdx.x < NP_) bins[threadIdx.x] = 0.f;
    __syncthreads();
    if (f < NF_) {
        int i0 = faces[3 * f], i1 = faces[3 * f + 1], i2 = faces[3 * f + 2];
        const float* vb = verts + (size_t)b * NV_ * 3;
        float ax = vb[3 * i0], ay = vb[3 * i0 + 1], az = vb[3 * i0 + 2];
        float bx = vb[3 * i1], by = vb[3 * i1 + 1], bz = vb[3 * i1 + 2];
        float cx = vb[3 * i2], cy = vb[3 * i2 + 1], cz = vb[3 * i2 + 2];
        float crx = by * cz - bz * cy;
        float cry = bz * cx - bx * cz;
        float crz = bx * cy - by * cx;
        float vol = fabsf(ax * crx + ay * cry + az * crz) * (1.0f / 6.0f);
        atomicAdd(&bins[face_part[f]], vol);
    }
    __syncthreads();
    if (threadIdx.x < NP_) atomicAdd(&ppv[b * NP_ + threadIdx.x], bins[threadIdx.x]);
}

// ---------------- KF: 64 rows/block, 4 waves = 2 row-halves x 2 K-splits ----------------
// Wave (wr,ws): rows n0+32*wr .. +31, chunks [ws*108, ws*108+108). The 2 waves of a K-split
// share one staged B double-buffer; each stages 6 of 12 tiles. One __syncthreads per iter
// (its vmcnt(0)+lgkmcnt(0) drain IS the stage/loadA synchronization — m97 structure).
__global__ __launch_bounds__(256) void kf_fused(const float* __restrict__ Hm,
                                                const unsigned short* __restrict__ Vc,
                                                const int* __restrict__ vert_fid,
                                                const int* __restrict__ face_part,
                                                const float* __restrict__ ppv,
                                                float* __restrict__ red) {
    __shared__ unsigned short Vb[2][2][BUF_HW];     // [split][dbuf][...] = 48 KB exactly
    const int tid  = threadIdx.x;
    const int lane = tid & 63;
    const int w    = tid >> 6;
    const int wr   = w & 1;                         // row half
    const int ws   = w >> 1;                        // K split
    const int lm   = lane & 15;
    const int kg   = lane >> 4;
    const int n0   = blockIdx.x * 64;
    const int rowbase = n0 + 32 * wr;
    const int r0c = min(rowbase + lm,      NHD_ - 1);
    const int r1c = min(rowbase + 16 + lm, NHD_ - 1);
    const float* Arow0 = Hm + (size_t)r0c * NV_;
    const float* Arow1 = Hm + (size_t)r1c * NV_;
    const int cbase = ws * ITERS;

    f32x4 acc0[12], acc1[12];
#pragma unroll
    for (int t = 0; t < 12; ++t) {
        acc0[t] = (f32x4){0.f, 0.f, 0.f, 0.f};
        acc1[t] = (f32x4){0.f, 0.f, 0.f, 0.f};
    }

    auto stageTiles = [&](int cc, int pp) {         // this wave's 6 of 12 tiles
        const unsigned short* src = Vc + (size_t)cc * BUF_HW;
        unsigned short* dst = &Vb[ws][pp][0];
#pragma unroll
        for (int i = 0; i < 6; ++i) {
            int t = wr * 6 + i;
            __builtin_amdgcn_global_load_lds(
                (const __attribute__((address_space(1))) void*)(src + t * 512 + lane * 8),
                (__attribute__((address_space(3))) void*)(dst + t * 512 + lane * 8), 16, 0, 0);
        }
    };
    auto loadA = [&](int cc, float2* ra, float2* rb) {
        int k0 = cc * 32 + kg * 8;
        if (cc == NCH - 1) {                        // partial tail chunk: guarded
            float ta[8], tb[8];
#pragma unroll
            for (int j = 0; j < 8; ++j) {
                int k = k0 + j;
                ta[j] = (k < NV_) ? Arow0[k] : 0.f;
                tb[j] = (k < NV_) ? Arow1[k] : 0.f;
            }
#pragma unroll
            for (int j = 0; j < 4; ++j) {
                ra[j] = make_float2(ta[2 * j], ta[2 * j + 1]);
                rb[j] = make_float2(tb[2 * j], tb[2 * j + 1]);
            }
        } else {
#pragma unroll
            for (int j = 0; j < 4; ++j) {
                ra[j] = *reinterpret_cast<const float2*>(Arow0 + k0 + 2 * j);
                rb[j] = *reinterpret_cast<const float2*>(Arow1 + k0 + 2 * j);
            }
        }
    };

    // prologue
    stageTiles(cbase, 0);
    float2 a[4], b[4];
    loadA(cbase, a, b);
    __syncthreads();

    int p = 0;
#pragma unroll 1
    for (int i = 0; i < ITERS; ++i) {
        const int c = cbase + i;
        // ds_read current B fragments (staged + barrier'd last iter)
        bf16x8 Bu[12];
        const unsigned short* bp = &Vb[ws][p][0] + lane * 8;
#pragma unroll
        for (int t = 0; t < 12; ++t)
            Bu[t] = *reinterpret_cast<const bf16x8*>(bp + t * 512);
        __builtin_amdgcn_sched_barrier(0);
        // consume current A into bf16 frags (frees a/b)
        bf16x8 Af0, Af1;
#pragma unroll
        for (int j = 0; j < 4; ++j) {
            Af0[2 * j]     = (__bf16)a[j].x;
            Af0[2 * j + 1] = (__bf16)a[j].y;
            Af1[2 * j]     = (__bf16)b[j].x;
            Af1[2 * j + 1] = (__bf16)b[j].y;
        }
        __builtin_amdgcn_sched_barrier(0);
        // issue next chunk's loads; they fly across the MFMAs, drained by the barrier
        if (i + 1 < ITERS) stageTiles(c + 1, p ^ 1);
        loadA((i + 1 < ITERS) ? c + 1 : c, a, b);
        __builtin_amdgcn_sched_barrier(0);
#pragma unroll
        for (int t = 0; t < 12; ++t)
            acc0[t] = __builtin_amdgcn_mfma_f32_16x16x32_bf16(Af0, Bu[t], acc0[t], 0, 0, 0);
#pragma unroll
        for (int t = 0; t < 12; ++t)
            acc1[t] = __builtin_amdgcn_mfma_f32_16x16x32_bf16(Af1, Bu[t], acc1[t], 0, 0, 0);
        __syncthreads();
        p ^= 1;
    }

    // ---- split-K merge: ws=1 dumps acc into dead Vb space (49152 B exactly) ----
    float* dump = reinterpret_cast<float*>(&Vb[0][0][0]);
    if (ws == 1) {
#pragma unroll
        for (int t = 0; t < 12; ++t) {
            *reinterpret_cast<f32x4*>(dump + wr * 6144 + (t * 64 + lane) * 4)        = acc0[t];
            *reinterpret_cast<f32x4*>(dump + wr * 6144 + ((12 + t) * 64 + lane) * 4) = acc1[t];
        }
    }
    __syncthreads();
    if (ws == 0) {
#pragma unroll
        for (int t = 0; t < 12; ++t) {
            acc0[t] += *reinterpret_cast<const f32x4*>(dump + wr * 6144 + (t * 64 + lane) * 4);
            acc1[t] += *reinterpret_cast<const f32x4*>(dump + wr * 6144 + ((12 + t) * 64 + lane) * 4);
        }
        // ---- epilogue (verified C layout): accX[t][r] = C[row][bd=t*16+lm];
        //      x: t=0..3, h: t=4..7, z: t=8..11; rows: acc0 kg*4+r, acc1 16+kg*4+r.
        int part0[4], part1[4];
        float val0[4], val1[4];
#pragma unroll
        for (int r = 0; r < 4; ++r) {
            int nn0 = rowbase + kg * 4 + r;
            int nn1 = rowbase + 16 + kg * 4 + r;
            part0[r] = face_part[vert_fid[min(nn0, NHD_ - 1)]];
            part1[r] = face_part[vert_fid[min(nn1, NHD_ - 1)]];
            val0[r] = (nn0 < NHD_) ? 1.f : 0.f;
            val1[r] = (nn1 < NHD_) ? 1.f : 0.f;
        }
        float sums[4][6];
#pragma unroll
        for (int t = 0; t < 4; ++t)
#pragma unroll
            for (int q = 0; q < 6; ++q) sums[t][q] = 0.f;
#pragma unroll
        for (int t = 0; t < 4; ++t) {
            int bcol = t * 16 + lm;
#pragma unroll
            for (int r = 0; r < 4; ++r) {
                {
                    float x = acc0[t][r], h = acc0[4 + t][r], z = acc0[8 + t][r];
                    float pwv = ((h < 0.f) ? (1.f - 100.f * h) : expf(-10.f * h)) * val0[r];
                    float wv  = ppv[bcol * NP_ + part0[r]] * val0[r];
                    sums[t][0] += pwv * x; sums[t][1] += pwv * z;
                    sums[t][2] += wv * x;  sums[t][3] += wv * z;
                    sums[t][4] += pwv;     sums[t][5] += wv;
                }
                {
                    float x = acc1[t][r], h = acc1[4 + t][r], z = acc1[8 + t][r];
                    float pwv = ((h < 0.f) ? (1.f - 100.f * h) : expf(-10.f * h)) * val1[r];
                    float wv  = ppv[bcol * NP_ + part1[r]] * val1[r];
                    sums[t][0] += pwv * x; sums[t][1] += pwv * z;
                    sums[t][2] += wv * x;  sums[t][3] += wv * z;
                    sums[t][4] += pwv;     sums[t][5] += wv;
                }
            }
        }
#pragma unroll
        for (int t = 0; t < 4; ++t)
#pragma unroll
            for (int q = 0; q < 6; ++q) {
                float v = sums[t][q];
                v += __shfl_xor(v, 16);
                v += __shfl_xor(v, 32);
                sums[t][q] = v;
            }
        if (kg == 0) {
#pragma unroll
            for (int t = 0; t < 4; ++t) {
                int bcol = t * 16 + lm;
#pragma unroll
                for (int q = 0; q < 6; ++q)
                    atomicAdd(&red[bcol * 6 + q], sums[t][q]);
            }
        }
    }
}

// ---------------- K5: finalize ----------------
__global__ __launch_bounds__(64) void k5_final(const float* __restrict__ red,
                                               float* __restrict__ out) {
    int b = threadIdx.x;
    if (b < B_) {
        float sp   = red[b * 6 + 4] + 1e-6f;
        float sw   = red[b * 6 + 5];
        float copx = red[b * 6 + 0] / sp;
        float copz = red[b * 6 + 1] / sp;
        float comx = red[b * 6 + 2] / sw;
        float comz = red[b * 6 + 3] / sw;
        float dx = comx - copx, dz = comz - copz;
        out[b] = sqrtf(dx * dx + dz * dz);
    }
}

extern "C" void kernel_launch(void* const* d_in, const int* in_sizes, int n_in,
                              void* d_out, int out_size, void* d_ws, size_t ws_size,
                              hipStream_t stream) {
    const float* verts     = (const float*)d_in[0];
    const float* Hm        = (const float*)d_in[1];
    const int*   faces     = (const int*)d_in[2];
    const int*   vert_fid  = (const int*)d_in[3];
    const int*   face_part = (const int*)d_in[4];
    char* ws = (char*)d_ws;
    float*          ppv = (float*)(ws + OFF_PPV);
    float*          red = (float*)(ws + OFF_RED);
    unsigned short* Vc  = (unsigned short*)(ws + OFF_VC);
    float* out = (float*)d_out;

    hipLaunchKernelGGL(k_init, dim3(1), dim3(256), 0, stream, (float*)ws);
    hipLaunchKernelGGL(k0v_pack, dim3((NCH * 12 * 512) / 256), dim3(256), 0, stream, verts, Vc);
    hipLaunchKernelGGL(k1_vol, dim3(54, 64), dim3(256), 0, stream, verts, faces, face_part, ppv);
    hipLaunchKernelGGL(kf_fused, dim3((NHD_ + 63) / 64), dim3(256), 0, stream,
                       Hm, Vc, vert_fid, face_part, ppv, red);
    hipLaunchKernelGGL(k5_final, dim3(1), dim3(64), 0, stream, red, out);
}

// Round 10
// 303.792 us; speedup vs baseline: 1.4500x; 1.4500x over previous
//
#include <hip/hip_runtime.h>
#include <cstdint>

#define B_    64
#define NV_   6890
#define NF_   13776
#define NHD_  20000
#define NP_   24
#define NCH   216           // ceil(6890/32) k-chunks of 32

// ---------------- workspace layout (bytes) ----------------
#define OFF_PPV   0u        // ppv [64][24] f32   6144   (zeroed by k_init)
#define OFF_RED   6144u     // red [64][6]  f32   1536   (zeroed by k_init)
#define OFF_VC    7680u     // Vc [216][12][64][8] bf16 = 2,654,208 B (fully rewritten)

typedef __attribute__((ext_vector_type(8))) __bf16 bf16x8;
typedef __attribute__((ext_vector_type(4))) float f32x4;

__device__ __forceinline__ unsigned short f2bf(float f) {
    unsigned u = __float_as_uint(f);
    u = (u + 0x7fffu + ((u >> 16) & 1u)) >> 16;   // RNE (no NaNs here)
    return (unsigned short)u;
}

// ---------------- K_init: zero ppv + red ----------------
__global__ __launch_bounds__(256) void k_init(float* __restrict__ z) {
    for (int i = threadIdx.x; i < 1920; i += 256) z[i] = 0.f;   // 1536 ppv + 384 red
}

// ---------------- K0v: pack V into MFMA-fragment order ----------------
// Vc[((c*12 + t)*64 + lane)*8 + j] = V_bf16[bd = t*16 + (lane&15)][k = c*32 + (lane>>4)*8 + j]
__global__ __launch_bounds__(256) void k0v_pack(const float* __restrict__ verts,
                                                unsigned short* __restrict__ Vc) {
    int idx = blockIdx.x * 256 + threadIdx.x;       // 216*12*512 = 1,327,104 total
    int j    = idx & 7;
    int lane = (idx >> 3) & 63;
    int ct   = idx >> 9;                            // c*12 + t
    int t    = ct % 12;
    int c    = ct / 12;
    int lm   = lane & 15;
    int kk   = (lane >> 4) * 8 + j;
    int bd   = t * 16 + lm;
    int d    = bd >> 6, b = bd & 63;
    int k    = c * 32 + kk;
    float v  = (k < NV_) ? verts[((size_t)b * NV_ + k) * 3 + d] : 0.f;
    Vc[idx] = f2bf(v);
}

// ---------------- K1: per-part volumes ----------------
__global__ __launch_bounds__(256) void k1_vol(const float* __restrict__ verts,
                                              const int* __restrict__ faces,
                                              const int* __restrict__ face_part,
                                              float* __restrict__ ppv) {
    __shared__ float bins[NP_];
    int b = blockIdx.y;
    int f = blockIdx.x * 256 + threadIdx.x;
    if (threadIdx.x < NP_) bins[threadIdx.x] = 0.f;
    __syncthreads();
    if (f < NF_) {
        int i0 = faces[3 * f], i1 = faces[3 * f + 1], i2 = faces[3 * f + 2];
        const float* vb = verts + (size_t)b * NV_ * 3;
        float ax = vb[3 * i0], ay = vb[3 * i0 + 1], az = vb[3 * i0 + 2];
        float bx = vb[3 * i1], by = vb[3 * i1 + 1], bz = vb[3 * i1 + 2];
        float cx = vb[3 * i2], cy = vb[3 * i2 + 1], cz = vb[3 * i2 + 2];
        float crx = by * cz - bz * cy;
        float cry = bz * cx - bx * cz;
        float crz = bx * cy - by * cx;
        float vol = fabsf(ax * crx + ay * cry + az * crz) * (1.0f / 6.0f);
        atomicAdd(&bins[face_part[f]], vol);
    }
    __syncthreads();
    if (threadIdx.x < NP_) atomicAdd(&ppv[b * NP_ + threadIdx.x], bins[threadIdx.x]);
}

// ---------------- KF: 1 wave/block, 32 rows, 3-deep all-DMA pipeline ----------------
// ALL loop vmem ops are global_load_lds (issue-pinned): 12 B + 4 A per chunk.
// Steady state: top-of-iter outstanding = S(c)+S(c+1) = 32; vmcnt(16) drains S(c),
// leaves S(c+1) flying; iter issues S(c+2). No barriers, no compiler-visible loads.
__global__ __launch_bounds__(64) void kf_fused(const float* __restrict__ Hm,
                                               const unsigned short* __restrict__ Vc,
                                               const int* __restrict__ vert_fid,
                                               const int* __restrict__ face_part,
                                               const float* __restrict__ ppv,
                                               float* __restrict__ red) {
    __shared__ unsigned short Bl[3][6144];          // 3 x 12 KB B buffers
    __shared__ float          Al[3][1024];          // 3 x 4 KB  A buffers (swizzled)
    const int lane = threadIdx.x;                   // 0..63
    const int lm   = lane & 15;
    const int kg   = lane >> 4;
    const int n0   = blockIdx.x * 32;               // 625 * 32 = 20000 exact
    const int arow = lane >> 3;                     // 0..7
    const int aseg = (lane & 7) ^ arow;             // swizzled global seg (inverse-swz source)

    f32x4 acc0[12], acc1[12];
#pragma unroll
    for (int t = 0; t < 12; ++t) {
        acc0[t] = (f32x4){0.f, 0.f, 0.f, 0.f};
        acc1[t] = (f32x4){0.f, 0.f, 0.f, 0.f};
    }

    auto stageB = [&](int c, int s) {               // 12 pinned DMA ops
        const unsigned short* src = Vc + (size_t)c * 6144 + lane * 8;
        unsigned short* dst = &Bl[s][lane * 8];
#pragma unroll
        for (int t = 0; t < 12; ++t)
            __builtin_amdgcn_global_load_lds(
                (const __attribute__((address_space(1))) void*)(src + t * 512),
                (__attribute__((address_space(3))) void*)(dst + t * 512), 16, 0, 0);
    };
    auto stageA = [&](int c, int s) {               // 4 pinned DMA ops, 32 rows x 128B
#pragma unroll
        for (int r = 0; r < 4; ++r) {
            const float* src = Hm + (size_t)(n0 + r * 8 + arow) * NV_ + c * 32 + aseg * 4;
            float* dst = &Al[s][r * 256 + lane * 4];    // uniform base + lane*16B
            __builtin_amdgcn_global_load_lds(
                (const __attribute__((address_space(1))) void*)src,
                (__attribute__((address_space(3))) void*)dst, 16, 0, 0);
        }
    };
    auto readA = [&](int s, bf16x8& Af0, bf16x8& Af1) {     // swizzled read: 2-way only
        const int x0 = ((2 * kg)     ^ (lm & 7)) * 4;
        const int x1 = ((2 * kg + 1) ^ (lm & 7)) * 4;
        f32x4 a0 = *(const f32x4*)&Al[s][lm * 32 + x0];
        f32x4 a1 = *(const f32x4*)&Al[s][lm * 32 + x1];
        f32x4 b0 = *(const f32x4*)&Al[s][(16 + lm) * 32 + x0];
        f32x4 b1 = *(const f32x4*)&Al[s][(16 + lm) * 32 + x1];
#pragma unroll
        for (int w = 0; w < 4; ++w) {
            Af0[w] = (__bf16)a0[w]; Af0[4 + w] = (__bf16)a1[w];
            Af1[w] = (__bf16)b0[w]; Af1[4 + w] = (__bf16)b1[w];
        }
    };
    auto mfma24 = [&](const bf16x8& Af0, const bf16x8& Af1, const bf16x8* Bu) {
#pragma unroll
        for (int t = 0; t < 12; ++t)
            acc0[t] = __builtin_amdgcn_mfma_f32_16x16x32_bf16(Af0, Bu[t], acc0[t], 0, 0, 0);
#pragma unroll
        for (int t = 0; t < 12; ++t)
            acc1[t] = __builtin_amdgcn_mfma_f32_16x16x32_bf16(Af1, Bu[t], acc1[t], 0, 0, 0);
    };
    auto step = [&](int c, int s, int s2) {         // main-loop body, s=(c%3), s2=(c+2)%3
        asm volatile("s_waitcnt vmcnt(16)" ::: "memory");
        __builtin_amdgcn_sched_barrier(0);
        bf16x8 Bu[12];
        const unsigned short* bp = &Bl[s][lane * 8];
#pragma unroll
        for (int t = 0; t < 12; ++t) Bu[t] = *(const bf16x8*)(bp + t * 512);
        bf16x8 Af0, Af1;
        readA(s, Af0, Af1);
        __builtin_amdgcn_sched_barrier(0);
        stageB(c + 2, s2);
        stageA(c + 2, s2);
        __builtin_amdgcn_sched_barrier(0);
        mfma24(Af0, Af1, Bu);
    };

    // prologue: S(0), S(1)  -> 32 outstanding
    stageB(0, 0); stageA(0, 0);
    stageB(1, 1); stageA(1, 1);

#pragma unroll 1
    for (int cc = 0; cc < 213; cc += 3) {           // 71 rounds; stages up to chunk 214
        step(cc, 0, 2);
        step(cc + 1, 1, 0);
        step(cc + 2, 2, 1);
    }

    // ---- peeled tail: chunks 213, 214, 215 ----
    {   // c = 213, slot 0; stage B(215) only (A-DMA for 215 would read OOB)
        asm volatile("s_waitcnt vmcnt(0)" ::: "memory");
        __builtin_amdgcn_sched_barrier(0);
        bf16x8 Bu[12];
        const unsigned short* bp = &Bl[0][lane * 8];
#pragma unroll
        for (int t = 0; t < 12; ++t) Bu[t] = *(const bf16x8*)(bp + t * 512);
        bf16x8 Af0, Af1; readA(0, Af0, Af1);
        __builtin_amdgcn_sched_barrier(0);
        stageB(215, 2);
        __builtin_amdgcn_sched_barrier(0);
        mfma24(Af0, Af1, Bu);
    }
    {   // c = 214, slot 1
        asm volatile("s_waitcnt vmcnt(0)" ::: "memory");
        __builtin_amdgcn_sched_barrier(0);
        bf16x8 Bu[12];
        const unsigned short* bp = &Bl[1][lane * 8];
#pragma unroll
        for (int t = 0; t < 12; ++t) Bu[t] = *(const bf16x8*)(bp + t * 512);
        bf16x8 Af0, Af1; readA(1, Af0, Af1);
        mfma24(Af0, Af1, Bu);
    }
    {   // c = 215 (partial: k 6880..6889), slot 2; A via guarded plain loads
        asm volatile("s_waitcnt vmcnt(0)" ::: "memory");
        __builtin_amdgcn_sched_barrier(0);
        bf16x8 Bu[12];
        const unsigned short* bp = &Bl[2][lane * 8];
#pragma unroll
        for (int t = 0; t < 12; ++t) Bu[t] = *(const bf16x8*)(bp + t * 512);
        const float* Arow0 = Hm + (size_t)(n0 + lm) * NV_;
        const float* Arow1 = Hm + (size_t)(n0 + 16 + lm) * NV_;
        bf16x8 Af0, Af1;
#pragma unroll
        for (int j = 0; j < 8; ++j) {
            int ko = kg * 8 + j;                    // valid iff ko < 10
            int k  = 6880 + ko;
            float fa = (ko < 10) ? Arow0[k] : 0.f;
            float fb = (ko < 10) ? Arow1[k] : 0.f;
            Af0[j] = (__bf16)fa;
            Af1[j] = (__bf16)fb;
        }
        mfma24(Af0, Af1, Bu);
    }

    // ---- epilogue: in-register (verified C layout): accX[t][r] = C[row][bd=t*16+lm];
    //      x: t=0..3, h: t=4..7, z: t=8..11; rows: acc0 kg*4+r, acc1 16+kg*4+r.
    int part0[4], part1[4];
#pragma unroll
    for (int r = 0; r < 4; ++r) {
        part0[r] = face_part[vert_fid[n0 + kg * 4 + r]];
        part1[r] = face_part[vert_fid[n0 + 16 + kg * 4 + r]];
    }
    float sums[4][6];                               // [t(b-group)][copx,copz,comx,comz,sp,sw]
#pragma unroll
    for (int t = 0; t < 4; ++t)
#pragma unroll
        for (int q = 0; q < 6; ++q) sums[t][q] = 0.f;

#pragma unroll
    for (int t = 0; t < 4; ++t) {
        int bcol = t * 16 + lm;
#pragma unroll
        for (int r = 0; r < 4; ++r) {
            {   // row group 0
                float x = acc0[t][r], h = acc0[4 + t][r], z = acc0[8 + t][r];
                float pwv = (h < 0.f) ? (1.f - 100.f * h) : expf(-10.f * h);
                float w = ppv[bcol * NP_ + part0[r]];
                sums[t][0] += pwv * x; sums[t][1] += pwv * z;
                sums[t][2] += w * x;   sums[t][3] += w * z;
                sums[t][4] += pwv;     sums[t][5] += w;
            }
            {   // row group 1
                float x = acc1[t][r], h = acc1[4 + t][r], z = acc1[8 + t][r];
                float pwv = (h < 0.f) ? (1.f - 100.f * h) : expf(-10.f * h);
                float w = ppv[bcol * NP_ + part1[r]];
                sums[t][0] += pwv * x; sums[t][1] += pwv * z;
                sums[t][2] += w * x;   sums[t][3] += w * z;
                sums[t][4] += pwv;     sums[t][5] += w;
            }
        }
    }
#pragma unroll
    for (int t = 0; t < 4; ++t)
#pragma unroll
        for (int q = 0; q < 6; ++q) {
            float v = sums[t][q];
            v += __shfl_xor(v, 16);
            v += __shfl_xor(v, 32);
            sums[t][q] = v;
        }
    if (kg == 0) {
#pragma unroll
        for (int t = 0; t < 4; ++t) {
            int bcol = t * 16 + lm;
#pragma unroll
            for (int q = 0; q < 6; ++q)
                atomicAdd(&red[bcol * 6 + q], sums[t][q]);
        }
    }
}

// ---------------- K5: finalize ----------------
__global__ __launch_bounds__(64) void k5_final(const float* __restrict__ red,
                                               float* __restrict__ out) {
    int b = threadIdx.x;
    if (b < B_) {
        float sp   = red[b * 6 + 4] + 1e-6f;
        float sw   = red[b * 6 + 5];
        float copx = red[b * 6 + 0] / sp;
        float copz = red[b * 6 + 1] / sp;
        float comx = red[b * 6 + 2] / sw;
        float comz = red[b * 6 + 3] / sw;
        float dx = comx - copx, dz = comz - copz;
        out[b] = sqrtf(dx * dx + dz * dz);
    }
}

extern "C" void kernel_launch(void* const* d_in, const int* in_sizes, int n_in,
                              void* d_out, int out_size, void* d_ws, size_t ws_size,
                              hipStream_t stream) {
    const float* verts     = (const float*)d_in[0];
    const float* Hm        = (const float*)d_in[1];
    const int*   faces     = (const int*)d_in[2];
    const int*   vert_fid  = (const int*)d_in[3];
    const int*   face_part = (const int*)d_in[4];
    char* ws = (char*)d_ws;
    float*          ppv = (float*)(ws + OFF_PPV);
    float*          red = (float*)(ws + OFF_RED);
    unsigned short* Vc  = (unsigned short*)(ws + OFF_VC);
    float* out = (float*)d_out;

    hipLaunchKernelGGL(k_init, dim3(1), dim3(256), 0, stream, (float*)ws);
    hipLaunchKernelGGL(k0v_pack, dim3((NCH * 12 * 512) / 256), dim3(256), 0, stream, verts, Vc);
    hipLaunchKernelGGL(k1_vol, dim3(54, 64), dim3(256), 0, stream, verts, faces, face_part, ppv);
    hipLaunchKernelGGL(kf_fused, dim3(NHD_ / 32), dim3(64), 0, stream,
                       Hm, Vc, vert_fid, face_part, ppv, red);
    hipLaunchKernelGGL(k5_final, dim3(1), dim3(64), 0, stream, red, out);
}